// Round 9
// baseline (260.453 us; speedup 1.0000x reference)
//
#include <hip/hip_runtime.h>

// SSIM loss, fused single pass, barrier-free, spill-free.
// [32,3,512,512] fp32 = 96 planes of 512x512. Each WAVE owns a 64x64 tile.
// Round-14: round-10/13 structure (verified absmax 0.0, main ~126us) with:
//  - SCALAR f32 math (v_pk_*_f32 is HALF-RATE on CDNA4: fp32 peak 157TF =
//    scalar rate already; pk bought nothing but code size)
//  - Gaussian weights pinned ONCE into SGPRs via opaque asm ("+s"): VOP3
//    can't take literals, and 77-phase straight-line code has no loop for
//    LICM, so round-10 re-materialized weight regs at every use (~88cy/phase
//    of v_mov). Now every v_fma_f32 reads its weight from an SGPR (1 SGPR
//    read per VOP3 is legal).
//  - __launch_bounds__(256,5): cap 102 regs (est. peak ~85) -> 5 blocks/CU
//    resident vs 4 (occupancy counter showed 39% = 4-block residency).
// Unchanged: 8-slot LDS ring, distance-5 prefetch, s_waitcnt vmcnt(10)
// (never 0), global_load_lds dwordx4 per-lane addr + uniform LDS dest,
// merged p|t slot (ds_read2 pairs at +0/+80), EXACT round-3 arithmetic
// and accumulation order.

#define IMG_H   512
#define IMG_W   512
#define TH      64          // tile rows/cols per wave
#define NCHUNK  7           // 7*11 = 77 row-phases (74 input rows needed)
#define LROW    160         // floats per LDS row-slot: p[0..79] | t[80..159]
#define RING    8           // ring slots (rows j..j+5 live)
#define SSIM_C1 1e-4f
#define SSIM_C2 9e-4f

// Gaussian taps, sigma=1.5, window 11 (w10-k == wk).
struct Ws { float w0,w1,w2,w3,w4,w5,w6,w7,w8,w9,w10; };

template<int I> __device__ __forceinline__ float WG(const Ws& W) {
    if constexpr (I == 0)  return W.w0;
    else if constexpr (I == 1)  return W.w1;
    else if constexpr (I == 2)  return W.w2;
    else if constexpr (I == 3)  return W.w3;
    else if constexpr (I == 4)  return W.w4;
    else if constexpr (I == 5)  return W.w5;
    else if constexpr (I == 6)  return W.w6;
    else if constexpr (I == 7)  return W.w7;
    else if constexpr (I == 8)  return W.w8;
    else if constexpr (I == 9)  return W.w9;
    else return W.w10;
}

// Async 16B/lane global->LDS. Global addr is per-lane; LDS dest is
// wave-uniform base + lane*16 (m97/m104).
__device__ __forceinline__ void gload16(const float* g, float* l) {
    __builtin_amdgcn_global_load_lds(
        (const __attribute__((address_space(1))) float*)g,
        (__attribute__((address_space(3))) float*)l, 16, 0, 0);
}

template<int PH>
__device__ __forceinline__ void phase(const float* __restrict__ pplw,
                                      const float* __restrict__ tplw,
                                      int r0, int j0, int lane4,
                                      float (*B)[LROW],
                                      int lane, bool lv, const Ws& GW,
                                      float (&accp)[11],  float (&acct)[11],
                                      float (&accpp)[11], float (&acctt)[11],
                                      float (&accpt)[11], float& lsum) {
    const int j = j0 + PH;

    // ---- issue async dwordx4 loads for row j+5 into ring slot (j+5)&7 ----
    // Row clamped so EVERY phase issues exactly 2 VMEM ops (vmcnt arithmetic
    // exact); clamped-row garbage never read (row-OOB phases skip conv).
    {
        const int rg  = r0 + j;                   // = (r0-5) + (j+5)
        const int rgc = min(max(rg, 0), IMG_H - 1);
        const int sI  = (j + 5) & (RING - 1);
        const float* ps = pplw + (size_t)rgc * IMG_W + lane4;  // per-lane
        const float* ts = tplw + (size_t)rgc * IMG_W + lane4;
        if (lv) {                                 // 18-20 lanes active
            gload16(ps, &B[sI][0]);               // p -> [0..79]
            gload16(ts, &B[sI][80]);              // t -> [80..159]
        }
    }

    // ---- counted wait: rows j+1..j+5 (10 loads) may stay in flight ----
    asm volatile("s_waitcnt vmcnt(10)" ::: "memory");

    // ---- horizontal 11-tap conv of p,t,p^2,t^2,pt + vertical scatter ----
    const int rgj = r0 - 5 + j;
    if (rgj >= 0 && rgj < IMG_H) {        // wave-uniform (r0, j uniform)
        const int sR = j & (RING - 1);
        const float* Lb = &B[sR][lane + 3];       // +0/+80 pairs -> ds_read2
        float hp = 0.f, ht = 0.f, hpp = 0.f, htt = 0.f, hpt = 0.f;
#define CV(i) { const float x = Lb[i]; const float y = Lb[i + 80];           \
                const float w = WG<i>(GW);        /* SGPR operand */         \
                hp  = fmaf(w, x, hp);                                        \
                ht  = fmaf(w, y, ht);                                        \
                const float wa = w * x;                                      \
                const float wb = w * y;                                      \
                hpp = fmaf(wa, x, hpp);                                      \
                htt = fmaf(wb, y, htt);                                      \
                hpt = fmaf(wa, y, hpt); }
        CV(0) CV(1) CV(2) CV(3) CV(4) CV(5) CV(6) CV(7) CV(8) CV(9) CV(10)
#undef CV
        // vertical scatter: row j feeds outputs l = j-10..j, slot = l%11
#define SCAT(s) { constexpr int m = ((s) - PH + 21) % 11;                    \
                  const float w = WG<10 - m>(GW); /* SGPR operand */         \
                  accp[s]  = fmaf(w, hp,  accp[s]);                          \
                  acct[s]  = fmaf(w, ht,  acct[s]);                          \
                  accpp[s] = fmaf(w, hpp, accpp[s]);                         \
                  acctt[s] = fmaf(w, htt, acctt[s]);                         \
                  accpt[s] = fmaf(w, hpt, accpt[s]); }
        SCAT(0) SCAT(1) SCAT(2) SCAT(3) SCAT(4) SCAT(5)
        SCAT(6) SCAT(7) SCAT(8) SCAT(9) SCAT(10)
#undef SCAT
    }
    // (row-OOB: conv of zero rows contributes zero -> skip is identical.)

    // ---- emit completed output row l = j-10 (slot (PH+1)%11), then reset ----
    constexpr int SE = (PH + 1) % 11;
    const int l = j - 10;
    if (l >= 0 && l < TH) {                       // wave-uniform branch
        const float mp = accp[SE], mt = acct[SE];
        const float mpp = mp * mp, mtt = mt * mt, mpt = mp * mt;
        const float sp  = accpp[SE] - mpp;
        const float st  = acctt[SE] - mtt;
        const float spt = accpt[SE] - mpt;
        const float num = (2.f * mpt + SSIM_C1) * (2.f * spt + SSIM_C2);
        const float den = (mpp + mtt + SSIM_C1) * (sp + st + SSIM_C2);
        lsum += num * __builtin_amdgcn_rcpf(den); // den >= C1*C2 > 0
    }
    accp[SE] = 0.f; acct[SE] = 0.f; accpp[SE] = 0.f;
    acctt[SE] = 0.f; accpt[SE] = 0.f;
}

__global__ __launch_bounds__(256, 5) void ssim_main(const float* __restrict__ pred,
                                                    const float* __restrict__ targ,
                                                    float* __restrict__ ws) {
    __shared__ float B[4][RING][LROW];    // [wave][slot][p|t]  = 20.0 KB
    __shared__ float wsum[4];

    const int tid  = threadIdx.x;
    const int lane = tid & 63;
    const int wid  = tid >> 6;

    // Pin the 11 Gaussian weights into SGPRs once (opaque to the folder).
    Ws GW;
    GW.w0  = 0.00102838f; GW.w1 = 0.00759879f; GW.w2 = 0.03600078f;
    GW.w3  = 0.10936070f; GW.w4 = 0.21300563f; GW.w5 = 0.26601180f;
    GW.w6  = 0.21300563f; GW.w7 = 0.10936070f; GW.w8 = 0.03600078f;
    GW.w9  = 0.00759879f; GW.w10 = 0.00102838f;
    asm volatile("" : "+s"(GW.w0), "+s"(GW.w1), "+s"(GW.w2), "+s"(GW.w3),
                      "+s"(GW.w4), "+s"(GW.w5), "+s"(GW.w6), "+s"(GW.w7),
                      "+s"(GW.w8), "+s"(GW.w9), "+s"(GW.w10));

    // 6144 tiles = 8 col-strips x 8 row-bands x 96 planes; 4 waves/block.
    const int gt    = __builtin_amdgcn_readfirstlane(blockIdx.x * 4 + wid);
    const int c0    = (gt & 7) * TH;
    const int r0    = ((gt >> 3) & 7) * TH;
    const int plane = gt >> 6;
    // Window base: column c0-8 (16B-aligned since c0%64==0).
    const float* pplw = pred + (size_t)plane * (IMG_H * IMG_W) + (c0 - 8);
    const float* tplw = targ + (size_t)plane * (IMG_H * IMG_W) + (c0 - 8);

    float (*W)[LROW] = B[wid];

    // Lane covers window cols [4*lane, 4*lane+3] = global [c0-8+4*lane, +3].
    const int  lane4 = lane * 4;
    const int  gc0   = c0 - 8 + lane4;
    const bool lv    = (lane < 20) && (gc0 >= 0) && (gc0 <= IMG_W - 4);

    // Pre-zero LDS words of permanently masked lanes (edge strips only):
    // gload_lds never touches them, so they stay zero all kernel.
    if (lane < 20 && !lv) {
        #pragma unroll
        for (int s = 0; s < RING; ++s) {
            #pragma unroll
            for (int w = 0; w < 4; ++w) {
                W[s][lane4 + w]      = 0.f;       // p section
                W[s][80 + lane4 + w] = 0.f;       // t section
            }
        }
    }

    // Prologue: issue rows j=0..4 (global rows r0-5..r0-1, clamped) into
    // ring slots 0..4 = 10 VMEM ops.
    #pragma unroll
    for (int r = 0; r < 5; ++r) {
        const int rg  = max(r0 - 5 + r, 0);       // top clamp only (r0<=448)
        const float* ps = pplw + (size_t)rg * IMG_W + lane4;
        const float* ts = tplw + (size_t)rg * IMG_W + lane4;
        if (lv) {
            gload16(ps, &W[r][0]);
            gload16(ts, &W[r][80]);
        }
    }

    float accp[11], acct[11], accpp[11], acctt[11], accpt[11];
    #pragma unroll
    for (int s = 0; s < 11; ++s) {
        accp[s] = 0.f; acct[s] = 0.f; accpp[s] = 0.f;
        acctt[s] = 0.f; accpt[s] = 0.f;
    }

    float lsum = 0.f;

    for (int chunk = 0; chunk < NCHUNK; ++chunk) {
        const int j0 = chunk * 11;
#define P(n) phase<n>(pplw, tplw, r0, j0, lane4, W, lane, lv, GW, \
                      accp, acct, accpp, acctt, accpt, lsum);
        P(0) P(1) P(2) P(3) P(4) P(5) P(6) P(7) P(8) P(9) P(10)
#undef P
    }

    // wave reduce -> one plain store per block into the workspace
    #pragma unroll
    for (int off = 32; off > 0; off >>= 1) lsum += __shfl_down(lsum, off);
    if (lane == 0) wsum[wid] = lsum;
    __syncthreads();
    if (tid == 0) ws[blockIdx.x] = wsum[0] + wsum[1] + wsum[2] + wsum[3];
}

__global__ __launch_bounds__(256) void ssim_finalize(const float* __restrict__ ws,
                                                     float* __restrict__ out) {
    __shared__ float wsum[4];
    const int tid  = threadIdx.x;
    const int lane = tid & 63;
    const int wid  = tid >> 6;
    float s = 0.f;
    #pragma unroll
    for (int i = 0; i < 6; ++i) s += ws[tid + 256 * i];   // 1536 = 6*256
    #pragma unroll
    for (int off = 32; off > 0; off >>= 1) s += __shfl_down(s, off);
    if (lane == 0) wsum[wid] = s;
    __syncthreads();
    if (tid == 0) {
        const float tot = wsum[0] + wsum[1] + wsum[2] + wsum[3];
        out[0] = 1.0f - tot * (1.0f / 25165824.0f);  // 1 - sum/(32*3*512*512)
    }
}

extern "C" void kernel_launch(void* const* d_in, const int* in_sizes, int n_in,
                              void* d_out, int out_size, void* d_ws, size_t ws_size,
                              hipStream_t stream) {
    (void)in_sizes; (void)n_in; (void)out_size; (void)ws_size;
    const float* pred = (const float*)d_in[0];
    const float* targ = (const float*)d_in[1];
    float* ws  = (float*)d_ws;          // 1536 floats of scratch
    float* out = (float*)d_out;

    ssim_main<<<dim3(1536), 256, 0, stream>>>(pred, targ, ws);
    ssim_finalize<<<1, 256, 0, stream>>>(ws, out);
}